// Round 1
// baseline (185.491 us; speedup 1.0000x reference)
//
#include <hip/hip_runtime.h>
#include <math.h>

// Problem constants (match reference setup_inputs)
#define BATCH 32
#define M 64
#define R 8
#define NPAIR (M * M)      // 4096
#define NTHREADS 256
#define NWAVES (NTHREADS / 64)

// One block per batch element. Greedy "MST" (Kruskal-style argmax loop) over
// pairmax[i][j] = max_k le[i,j,k], which is exactly equivalent to the
// reference's greedy over the full [M,M,R] tensor because blocking is
// monotone and always blocks all R channels of a pair.
__global__ __launch_bounds__(NTHREADS)
void tree_crf_mst_kernel(const float* __restrict__ le,   // [B, M, M, R]
                         const int* __restrict__ tree,   // [B, M, 3]
                         float* __restrict__ partial)    // [B]
{
    __shared__ float pm[NPAIR];                      // 16 KB pair maxima
    __shared__ unsigned long long part_mask[M];      // partition membership bitmasks
    __shared__ float red_val[NWAVES];
    __shared__ int   red_idx[NWAVES];

    const int b = blockIdx.x;
    const int t = threadIdx.x;
    const float* bl = le + (size_t)b * NPAIR * R;

    // ---- 1. pairmax over k (coalesced float4 loads) ----
    for (int p = t; p < NPAIR; p += NTHREADS) {
        const float4 v0 = *reinterpret_cast<const float4*>(bl + (size_t)p * R);
        const float4 v1 = *reinterpret_cast<const float4*>(bl + (size_t)p * R + 4);
        float mx = fmaxf(fmaxf(fmaxf(v0.x, v0.y), fmaxf(v0.z, v0.w)),
                         fmaxf(fmaxf(v1.x, v1.y), fmaxf(v1.z, v1.w)));
        pm[p] = mx;
    }
    if (t < M) part_mask[t] = 1ull << t;
    __syncthreads();

    float mst_e = 0.0f;

    for (int it = 0; it < M; ++it) {
        // ---- per-thread scan (16 entries each, conflict-free stride-256) ----
        float bv = -INFINITY;
        int   bi = NPAIR;  // sentinel (larger than any real index)
        #pragma unroll
        for (int q = 0; q < NPAIR / NTHREADS; ++q) {
            int p = t + q * NTHREADS;
            float v = pm[p];
            if (v > bv || (v == bv && p < bi)) { bv = v; bi = p; }
        }
        // ---- wave (64-lane) argmax reduce, first-index tie-break ----
        #pragma unroll
        for (int off = 32; off > 0; off >>= 1) {
            float ov = __shfl_down(bv, off);
            int   oi = __shfl_down(bi, off);
            if (ov > bv || (ov == bv && oi < bi)) { bv = ov; bi = oi; }
        }
        if ((t & 63) == 0) { red_val[t >> 6] = bv; red_idx[t >> 6] = bi; }
        __syncthreads();

        // ---- all threads redundantly reduce the NWAVES leaders ----
        float gbv = red_val[0];
        int   gbi = red_idx[0];
        #pragma unroll
        for (int w = 1; w < NWAVES; ++w) {
            float ov = red_val[w];
            int   oi = red_idx[w];
            if (ov > gbv || (ov == gbv && oi < gbi)) { gbv = ov; gbi = oi; }
        }
        const int i = gbi >> 6;
        const int j = gbi & (M - 1);
        // broadcast LDS reads (same address across lanes -> free)
        const unsigned long long mf = part_mask[i];
        const unsigned long long mt = part_mask[j];
        __syncthreads();  // everyone has read part_mask before it is rewritten

        if (gbv > -INFINITY) {
            mst_e += gbv;  // identical on every thread
            if (t < M) {
                const unsigned long long merged = mf | mt;
                unsigned long long rb = 0;
                if ((mf >> t) & 1ull) rb |= mt;
                if ((mt >> t) & 1ull) rb |= mf;
                while (rb) {
                    int c = __ffsll((long long)rb) - 1;
                    rb &= rb - 1;
                    pm[t * M + c] = -INFINITY;
                }
                if ((merged >> t) & 1ull) part_mask[t] = merged;
            }
        }
        __syncthreads();  // pm/part_mask updates visible to next iteration
    }

    // ---- label tree score: 64 lanes gather, (0,0,0) contributes 0 ----
    float ls = 0.0f;
    if (t < M) {
        const int* tr = tree + ((size_t)b * M + t) * 3;
        const int i0 = tr[0], i1 = tr[1], i2 = tr[2];
        if (!((i0 == 0) && (i1 == 0) && (i2 == 0))) {
            ls = bl[((size_t)(i0 * M + i1)) * R + i2];
        }
    }
    if (t < 64) {
        #pragma unroll
        for (int off = 32; off > 0; off >>= 1) ls += __shfl_down(ls, off);
    }
    if (t == 0) partial[b] = mst_e - ls;
}

// Fixed-order final reduction -> deterministic scalar output.
__global__ void tree_crf_reduce_kernel(const float* __restrict__ partial,
                                       float* __restrict__ out)
{
    if (threadIdx.x == 0 && blockIdx.x == 0) {
        float s = 0.0f;
        for (int b = 0; b < BATCH; ++b) s += partial[b];
        out[0] = s * (1.0f / BATCH);
    }
}

extern "C" void kernel_launch(void* const* d_in, const int* in_sizes, int n_in,
                              void* d_out, int out_size, void* d_ws, size_t ws_size,
                              hipStream_t stream) {
    const float* le   = (const float*)d_in[0];   // [32, 64, 64, 8] f32
    const int*   tree = (const int*)d_in[1];     // [32, 64, 3] i32
    float* out = (float*)d_out;                  // [1] f32
    float* partial = (float*)d_ws;               // 32 floats of scratch

    tree_crf_mst_kernel<<<BATCH, NTHREADS, 0, stream>>>(le, tree, partial);
    tree_crf_reduce_kernel<<<1, 64, 0, stream>>>(partial, out);
}

// Round 2
// 162.615 us; speedup vs baseline: 1.1407x; 1.1407x over previous
//
#include <hip/hip_runtime.h>
#include <math.h>

#define BATCH 32
#define M 64
#define R 8
typedef unsigned long long u64;

// Exact tie-break: prefer (v,c) over (bv,bc) if larger value, or equal value
// with smaller flat column index (reference argmax returns first flat index).
__device__ __forceinline__ void better(float v, int c, float& bv, int& bc) {
    if (v > bv || (v == bv && c < bc)) { bv = v; bc = c; }
}

__device__ __forceinline__ u64 shfl_u64(u64 v, int src) {
    int lo = __shfl((int)(unsigned)v, src);
    int hi = __shfl((int)(unsigned)(v >> 32), src);
    return ((u64)(unsigned)hi << 32) | (unsigned)lo;
}

// Row scan: lane t scans its own (swizzled) 64-float row -> (rmax, rarg).
// Swizzle: physical float4-slot = logical_slot ^ (t & 7)  (256B-row XOR fix).
__device__ __forceinline__ void row_argmax(const float* pm, int t,
                                           float& rmax, int& rarg) {
    const float4* row4 = reinterpret_cast<const float4*>(pm) + (t << 4);
    const int x = t & 7;
    float4 v = row4[x];            // logical slot 0
    float bx = v.x, by = v.y, bz = v.z, bw = v.w;
    int cx = 0, cy = 1, cz = 2, cw = 3;
    #pragma unroll
    for (int s = 1; s < 16; ++s) {
        float4 u = row4[s ^ x];
        const int c0 = s << 2;
        if (u.x > bx) { bx = u.x; cx = c0; }
        if (u.y > by) { by = u.y; cy = c0 + 1; }
        if (u.z > bz) { bz = u.z; cz = c0 + 2; }
        if (u.w > bw) { bw = u.w; cw = c0 + 3; }
    }
    rmax = bx; rarg = cx;          // strict > kept earliest slot per chain;
    better(by, cy, rmax, rarg);    // cross-chain combine is exact
    better(bz, cz, rmax, rarg);
    better(bw, cw, rmax, rarg);
}

// One wave per batch element. Lane t owns row t of pairmax -> no barriers in
// the greedy loop; all cross-lane traffic via shfl/ballot.
__global__ __launch_bounds__(64)
void tree_crf_mst_kernel(const float* __restrict__ le,   // [B, M, M, R]
                         const int* __restrict__ tree,   // [B, M, 3]
                         float* __restrict__ partial)    // [B]
{
    __shared__ float pm[M * M];                          // 16 KB, swizzled rows
    const int b = blockIdx.x;
    const int t = threadIdx.x;                           // lane, owns row t
    const float* bl = le + (size_t)b * M * M * R;

    // ---- label tree score gather (issued early to hide global latency) ----
    const int* tr = tree + ((size_t)b * M + t) * 3;
    const int i0 = tr[0], i1 = tr[1], i2 = tr[2];
    float ls = 0.0f;
    if (!((i0 == 0) & (i1 == 0) & (i2 == 0)))            // (0,0,0) contributes 0
        ls = bl[(size_t)((i0 << 6) | i1) * R + i2];

    // ---- stage pairmax[r][c] = max_k le[r,c,k] into swizzled LDS ----
    const float4* g4 = reinterpret_cast<const float4*>(bl);
    #pragma unroll 4
    for (int r = 0; r < M; ++r) {
        const int p = (r << 6) | t;                      // pair (r, t)
        float4 a = g4[2 * p];
        float4 c4 = g4[2 * p + 1];
        float mx = fmaxf(fmaxf(fmaxf(a.x, a.y), fmaxf(a.z, a.w)),
                         fmaxf(fmaxf(c4.x, c4.y), fmaxf(c4.z, c4.w)));
        pm[(r << 6) + (((((t >> 2) ^ (r & 7))) << 2) | (t & 3))] = mx;
    }
    __syncthreads();                                     // only barrier needed

    // ---- initial per-row argmax ----
    float rmax; int rarg;
    row_argmax(pm, t, rmax, rarg);

    u64 mask = 1ull << t;                                // partition of node t
    bool needRe = false;
    float mst = 0.0f;
    const int x = t & 7;
    float* rowp = pm + (t << 6);

    for (int it = 0; it < M; ++it) {
        // lazily rescan rows whose cached argmax got blocked
        if (__ballot(needRe)) {
            if (needRe) row_argmax(pm, t, rmax, rarg);
            needRe = false;
        }
        // global max value via fmax butterfly (all lanes converge)
        float g = rmax;
        #pragma unroll
        for (int off = 1; off < 64; off <<= 1)
            g = fmaxf(g, __shfl_xor(g, off));
        if (g == -INFINITY) break;                       // uniform; nothing left
        // winner = lowest lane holding g (= smallest row = reference tie-break)
        const u64 sel = __ballot(rmax == g);
        const int gi = __ffsll((long long)sel) - 1;
        const int gj = __shfl(rarg, gi);
        mst += g;                                        // identical on all lanes
        const u64 mf = shfl_u64(mask, gi);
        const u64 mt = shfl_u64(mask, gj);
        const u64 merged = mf | mt;
        if ((merged >> t) & 1) mask = merged;
        // block P x Q and Q x P (row-t slice); lane t only touches row t
        u64 rb = (((mf >> t) & 1) ? mt : 0ull) | (((mt >> t) & 1) ? mf : 0ull);
        if (rb) {
            needRe = (rb >> rarg) & 1;                   // argmax entry killed?
            do {
                const int c = __ffsll((long long)rb) - 1;
                rb &= rb - 1;
                rowp[((((c >> 2) ^ x)) << 2) | (c & 3)] = -INFINITY;
            } while (rb);
        }
    }

    // ---- wave sum of label scores; lane 0 writes the batch partial ----
    #pragma unroll
    for (int off = 32; off; off >>= 1) ls += __shfl_down(ls, off);
    if (t == 0) partial[b] = mst - ls;
}

// Fixed-order final reduction -> deterministic scalar output.
__global__ void tree_crf_reduce_kernel(const float* __restrict__ partial,
                                       float* __restrict__ out)
{
    if (threadIdx.x == 0 && blockIdx.x == 0) {
        float s = 0.0f;
        for (int i = 0; i < BATCH; ++i) s += partial[i];
        out[0] = s * (1.0f / BATCH);
    }
}

extern "C" void kernel_launch(void* const* d_in, const int* in_sizes, int n_in,
                              void* d_out, int out_size, void* d_ws, size_t ws_size,
                              hipStream_t stream) {
    const float* le   = (const float*)d_in[0];   // [32, 64, 64, 8] f32
    const int*   tree = (const int*)d_in[1];     // [32, 64, 3] i32
    float* out = (float*)d_out;                  // [1] f32
    float* partial = (float*)d_ws;               // 32 floats of scratch

    tree_crf_mst_kernel<<<BATCH, 64, 0, stream>>>(le, tree, partial);
    tree_crf_reduce_kernel<<<1, 64, 0, stream>>>(partial, out);
}

// Round 3
// 153.376 us; speedup vs baseline: 1.2094x; 1.0602x over previous
//
#include <hip/hip_runtime.h>
#include <math.h>

#define BATCH 32
#define M 64
#define R 8
typedef unsigned long long u64;

// XOR swizzle of the float4 slot within a 64-float (256 B) LDS row: breaks the
// 32-way bank conflict of same-column access across rows (G4 recipe).
#define SWZ_SLOT(r, s) ((s) ^ ((r) & 7))
#define PM_IDX(r, c) ((((r) << 6)) + ((SWZ_SLOT((r), (c) >> 2) << 2) | ((c) & 3)))

// Exact tie-break: prefer larger value; on equal value prefer smaller column
// (reference argmax returns the first flat index).
__device__ __forceinline__ void better(float v, int c, float& bv, int& bc) {
    if (v > bv || (v == bv && c < bc)) { bv = v; bc = c; }
}

// Lane t scans its own swizzled 64-float row -> (rmax, rarg).
__device__ __forceinline__ void row_argmax(const float* pm, int t,
                                           float& rmax, int& rarg) {
    const float4* row4 = reinterpret_cast<const float4*>(pm) + (t << 4);
    const int x = t & 7;
    float4 v = row4[x];                       // logical slot 0
    float bx = v.x, by = v.y, bz = v.z, bw = v.w;
    int cx = 0, cy = 1, cz = 2, cw = 3;
    #pragma unroll
    for (int s = 1; s < 16; ++s) {
        float4 u = row4[s ^ x];
        const int c0 = s << 2;
        if (u.x > bx) { bx = u.x; cx = c0; }       // strict > keeps earliest slot
        if (u.y > by) { by = u.y; cy = c0 + 1; }
        if (u.z > bz) { bz = u.z; cz = c0 + 2; }
        if (u.w > bw) { bw = u.w; cw = c0 + 3; }
    }
    rmax = bx; rarg = cx;
    better(by, cy, rmax, rarg);
    better(bz, cz, rmax, rarg);
    better(bw, cw, rmax, rarg);
}

// Wave-wide max via DPP (VALU pipe, ~25 cyc) + readlane broadcast.
// old-operand = own value => lanes with invalid DPP source fmax with self.
__device__ __forceinline__ float wave_max_bcast(float g) {
    int v = __float_as_int(g);
    #define DPP_STEP(ctrl)                                                   \
        { int o = __builtin_amdgcn_update_dpp(v, v, (ctrl), 0xf, 0xf, false);\
          g = fmaxf(g, __int_as_float(o)); v = __float_as_int(g); }
    DPP_STEP(0x111)  // row_shr:1
    DPP_STEP(0x112)  // row_shr:2
    DPP_STEP(0x114)  // row_shr:4
    DPP_STEP(0x118)  // row_shr:8   -> lanes 15/31/47/63 hold their row max
    DPP_STEP(0x142)  // row_bcast:15
    DPP_STEP(0x143)  // row_bcast:31 -> lane 63 holds the wave max
    #undef DPP_STEP
    return __int_as_float(__builtin_amdgcn_readlane(v, 63));
}

__device__ __forceinline__ u64 readlane_u64(u64 v, int lane) {
    unsigned lo = (unsigned)__builtin_amdgcn_readlane((int)(unsigned)v, lane);
    unsigned hi = (unsigned)__builtin_amdgcn_readlane((int)(v >> 32), lane);
    return ((u64)hi << 32) | lo;
}

// One block per batch element. 4 waves stage pairmax; wave 0 runs the greedy
// loop barrier-free (lane t owns row t); wave 1 computes the label score
// concurrently; waves 2-3 retire after staging.
__global__ __launch_bounds__(256)
void tree_crf_mst_kernel(const float* __restrict__ le,   // [B, M, M, R]
                         const int* __restrict__ tree,   // [B, M, 3]
                         float* __restrict__ mst_out,    // [B]
                         float* __restrict__ ls_out)     // [B]
{
    __shared__ __align__(16) float pm[M * M];            // 16 KB swizzled rows
    const int b = blockIdx.x;
    const int tt = threadIdx.x;
    const float* bl = le + (size_t)b * M * M * R;
    const float4* g4 = reinterpret_cast<const float4*>(bl);

    // ---- stage pairmax[r][c] = max_k le[r,c,k] (all 4 waves) ----
    #pragma unroll
    for (int p = tt; p < M * M; p += 256) {
        const float4 a  = g4[2 * p];
        const float4 c4 = g4[2 * p + 1];
        const float mx = fmaxf(fmaxf(fmaxf(a.x, a.y), fmaxf(a.z, a.w)),
                               fmaxf(fmaxf(c4.x, c4.y), fmaxf(c4.z, c4.w)));
        const int r = p >> 6, c = p & 63;
        pm[PM_IDX(r, c)] = mx;
    }
    __syncthreads();                                     // only barrier

    const int wave = tt >> 6;
    const int t = tt & 63;

    if (wave == 1) {
        // ---- label tree score (overlaps wave 0's greedy loop) ----
        const int* tr = tree + ((size_t)b * M + t) * 3;
        const int i0 = tr[0], i1 = tr[1], i2 = tr[2];
        float ls = 0.0f;
        if (!((i0 == 0) & (i1 == 0) & (i2 == 0)))        // (0,0,0) contributes 0
            ls = bl[(size_t)((i0 << 6) | i1) * R + i2];
        #pragma unroll
        for (int off = 32; off; off >>= 1) ls += __shfl_down(ls, off);
        if (t == 0) ls_out[b] = ls;
        return;
    }
    if (wave != 0) return;

    // ---- greedy Kruskal-style loop, wave 0 only, no barriers ----
    float rmax; int rarg;
    row_argmax(pm, t, rmax, rarg);

    u64 mask = 1ull << t;                                // partition of node t
    bool needRe = false;
    float mst = 0.0f;
    const int x = t & 7;
    float* rowp = pm + (t << 6);

    for (int it = 0; it < M; ++it) {
        if (__ballot(needRe)) {                          // lazy row rescans
            if (needRe) row_argmax(pm, t, rmax, rarg);
            needRe = false;
        }
        const float g = wave_max_bcast(rmax);            // uniform global max
        if (g == -INFINITY) break;                       // nothing left
        const u64 sel = __ballot(rmax == g);
        const int gi = __ffsll((long long)sel) - 1;      // smallest row wins tie
        const int gj = __builtin_amdgcn_readlane(rarg, gi);
        mst += g;                                        // identical on all lanes
        const u64 mf = readlane_u64(mask, gi);
        const u64 mt = readlane_u64(mask, gj);
        const u64 merged = mf | mt;
        if ((merged >> t) & 1) mask = merged;
        // block P x Q  and  Q x P (row-t slice); lane t only touches row t
        u64 rb = (((mf >> t) & 1) ? mt : 0ull) | (((mt >> t) & 1) ? mf : 0ull);
        if (rb) {
            needRe = (rb >> rarg) & 1;                   // cached argmax killed?
            u64 v = rb;
            while (v) {
                const int c = __ffsll((long long)v) - 1;
                const int nib = c >> 2;
                const unsigned bits = (unsigned)((rb >> (nib << 2)) & 0xFull);
                float* slotp = rowp + ((nib ^ x) << 2);
                if (bits == 0xFu) {                      // whole nibble: 16B write
                    *reinterpret_cast<float4*>(slotp) =
                        make_float4(-INFINITY, -INFINITY, -INFINITY, -INFINITY);
                } else {
                    unsigned bb = bits;
                    do { const int k = __ffs(bb) - 1; bb &= bb - 1;
                         slotp[k] = -INFINITY; } while (bb);
                }
                v &= ~(0xFull << (nib << 2));
            }
        }
    }
    if (t == 0) mst_out[b] = mst;
}

// Fixed-order final reduction -> deterministic scalar output.
__global__ void tree_crf_reduce_kernel(const float* __restrict__ mst_p,
                                       const float* __restrict__ ls_p,
                                       float* __restrict__ out)
{
    if (threadIdx.x == 0 && blockIdx.x == 0) {
        float s = 0.0f;
        for (int i = 0; i < BATCH; ++i) s += mst_p[i] - ls_p[i];
        out[0] = s * (1.0f / BATCH);
    }
}

extern "C" void kernel_launch(void* const* d_in, const int* in_sizes, int n_in,
                              void* d_out, int out_size, void* d_ws, size_t ws_size,
                              hipStream_t stream) {
    const float* le   = (const float*)d_in[0];   // [32, 64, 64, 8] f32
    const int*   tree = (const int*)d_in[1];     // [32, 64, 3] i32
    float* out = (float*)d_out;                  // [1] f32
    float* mst_p = (float*)d_ws;                 // [32]
    float* ls_p  = mst_p + BATCH;                // [32]

    tree_crf_mst_kernel<<<BATCH, 256, 0, stream>>>(le, tree, mst_p, ls_p);
    tree_crf_reduce_kernel<<<1, 64, 0, stream>>>(mst_p, ls_p, out);
}

// Round 4
// 85.493 us; speedup vs baseline: 2.1697x; 1.7940x over previous
//
#include <hip/hip_runtime.h>
#include <math.h>

#define BATCH 32
#define M 64
#define R 8
typedef unsigned long long u64;

// XOR swizzle of the float4 slot within a 64-float (256 B) LDS row (G4 recipe).
#define SWZ_SLOT(r, s) ((s) ^ ((r) & 7))
#define PM_IDX(r, c) ((((r) << 6)) + ((SWZ_SLOT((r), (c) >> 2) << 2) | ((c) & 3)))

// Wave-wide max via DPP (VALU pipe) + readlane broadcast.
// old-operand = own value => lanes with invalid DPP source fmax with self.
__device__ __forceinline__ float wave_max_bcast(float g) {
    int v = __float_as_int(g);
    #define DPP_STEP(ctrl)                                                   \
        { int o = __builtin_amdgcn_update_dpp(v, v, (ctrl), 0xf, 0xf, false);\
          g = fmaxf(g, __int_as_float(o)); v = __float_as_int(g); }
    DPP_STEP(0x111)  // row_shr:1
    DPP_STEP(0x112)  // row_shr:2
    DPP_STEP(0x114)  // row_shr:4
    DPP_STEP(0x118)  // row_shr:8   -> lanes 15/31/47/63 hold their row max
    DPP_STEP(0x142)  // row_bcast:15
    DPP_STEP(0x143)  // row_bcast:31 -> lane 63 holds the wave max
    #undef DPP_STEP
    return __int_as_float(__builtin_amdgcn_readlane(v, 63));
}

__device__ __forceinline__ u64 readlane_u64(u64 v, int lane) {
    unsigned lo = (unsigned)__builtin_amdgcn_readlane((int)(unsigned)v, lane);
    unsigned hi = (unsigned)__builtin_amdgcn_readlane((int)(v >> 32), lane);
    return ((u64)hi << 32) | lo;
}

// One block per batch element. 4 waves stage pairmax into LDS; wave 0 then
// pulls its row into REGISTERS and runs the greedy loop with zero LDS/global
// traffic; wave 1 computes the label score concurrently; waves 2-3 retire.
__global__ __launch_bounds__(256)
void tree_crf_mst_kernel(const float* __restrict__ le,   // [B, M, M, R]
                         const int* __restrict__ tree,   // [B, M, 3]
                         float* __restrict__ mst_out,    // [B]
                         float* __restrict__ ls_out)     // [B]
{
    __shared__ __align__(16) float pm[M * M];            // 16 KB swizzled rows
    const int b = blockIdx.x;
    const int tt = threadIdx.x;
    const float* bl = le + (size_t)b * M * M * R;
    const float4* g4 = reinterpret_cast<const float4*>(bl);

    // ---- stage pairmax[r][c] = max_k le[r,c,k] (all 4 waves, coalesced) ----
    #pragma unroll
    for (int p = tt; p < M * M; p += 256) {
        const float4 a  = g4[2 * p];
        const float4 c4 = g4[2 * p + 1];
        const float mx = fmaxf(fmaxf(fmaxf(a.x, a.y), fmaxf(a.z, a.w)),
                               fmaxf(fmaxf(c4.x, c4.y), fmaxf(c4.z, c4.w)));
        const int rr = p >> 6, cc = p & 63;
        pm[PM_IDX(rr, cc)] = mx;
    }
    __syncthreads();                                     // only barrier

    const int wave = tt >> 6;
    const int t = tt & 63;

    if (wave == 1) {
        // ---- label tree score (overlaps wave 0's greedy loop) ----
        const int* tr = tree + ((size_t)b * M + t) * 3;
        const int i0 = tr[0], i1 = tr[1], i2 = tr[2];
        float ls = 0.0f;
        if (!((i0 == 0) & (i1 == 0) & (i2 == 0)))        // (0,0,0) contributes 0
            ls = bl[(size_t)((i0 << 6) | i1) * R + i2];
        #pragma unroll
        for (int off = 32; off; off >>= 1) ls += __shfl_down(ls, off);
        if (t == 0) ls_out[b] = ls;
        return;
    }
    if (wave != 0) return;

    // ---- lane t pulls row t into registers (logical column order) ----
    float r[M];
    {
        const float4* row4 = reinterpret_cast<const float4*>(pm) + (t << 4);
        const int x = t & 7;
        #pragma unroll
        for (int s = 0; s < 16; ++s) {
            const float4 v = row4[s ^ x];
            r[4 * s + 0] = v.x; r[4 * s + 1] = v.y;
            r[4 * s + 2] = v.z; r[4 * s + 3] = v.w;
        }
    }

    u64 mask = 1ull << t;                                // partition of node t
    float mst = 0.0f;

    #pragma unroll 1                                     // keep loop rolled
    for (int it = 0; it < M; ++it) {
        // ---- per-lane row max: unrolled fmax tree (regs only, depth 6) ----
        float w[32];
        #pragma unroll
        for (int i = 0; i < 32; ++i) w[i] = fmaxf(r[i], r[i + 32]);
        #pragma unroll
        for (int s = 16; s > 0; s >>= 1) {
            #pragma unroll
            for (int i = 0; i < s; ++i) w[i] = fmaxf(w[i], w[i + s]);
        }
        const float m = w[0];

        // ---- global max + winner lane (smallest row wins ties) ----
        const float g = wave_max_bcast(m);
        if (g == -INFINITY) break;                       // uniform; nothing left
        const u64 sel = __ballot(m == g);
        const int gi = __ffsll((long long)sel) - 1;

        // ---- winner's column: first (smallest) index equal to g ----
        int idx = M;
        #pragma unroll
        for (int i = M - 1; i >= 0; --i)                 // descending overwrite
            if (r[i] == g) idx = i;                      //  -> smallest index
        const int gj = __builtin_amdgcn_readlane(idx, gi);

        mst += g;                                        // identical on all lanes
        const u64 mf = readlane_u64(mask, gi);
        const u64 mt = readlane_u64(mask, gj);
        const u64 merged = mf | mt;
        if ((merged >> t) & 1) mask = merged;

        // ---- block P x Q and Q x P (row-t slice), pure cndmask kills ----
        const u64 rb = (((mf >> t) & 1) ? mt : 0ull) |
                       (((mt >> t) & 1) ? mf : 0ull);
        const unsigned rlo = (unsigned)rb, rhi = (unsigned)(rb >> 32);
        #pragma unroll
        for (int i = 0; i < 32; ++i) {
            if ((rlo >> i) & 1u) r[i]      = -INFINITY;
            if ((rhi >> i) & 1u) r[i + 32] = -INFINITY;
        }
    }
    if (t == 0) mst_out[b] = mst;
}

// Fixed-order final reduction -> deterministic scalar output.
__global__ void tree_crf_reduce_kernel(const float* __restrict__ mst_p,
                                       const float* __restrict__ ls_p,
                                       float* __restrict__ out)
{
    if (threadIdx.x == 0 && blockIdx.x == 0) {
        float s = 0.0f;
        for (int i = 0; i < BATCH; ++i) s += mst_p[i] - ls_p[i];
        out[0] = s * (1.0f / BATCH);
    }
}

extern "C" void kernel_launch(void* const* d_in, const int* in_sizes, int n_in,
                              void* d_out, int out_size, void* d_ws, size_t ws_size,
                              hipStream_t stream) {
    const float* le   = (const float*)d_in[0];   // [32, 64, 64, 8] f32
    const int*   tree = (const int*)d_in[1];     // [32, 64, 3] i32
    float* out = (float*)d_out;                  // [1] f32
    float* mst_p = (float*)d_ws;                 // [32]
    float* ls_p  = mst_p + BATCH;                // [32]

    tree_crf_mst_kernel<<<BATCH, 256, 0, stream>>>(le, tree, mst_p, ls_p);
    tree_crf_reduce_kernel<<<1, 64, 0, stream>>>(mst_p, ls_p, out);
}